// Round 10
// baseline (76.701 us; speedup 1.0000x reference)
//
#include <hip/hip_runtime.h>

#define BATCH 1024
#define INSZ 4096
#define NH 8
#define TPB 512
#define LDX 40  // padded stride (elems) for all [*][32] tiles; 80B rows, 16B-aligned

typedef __attribute__((ext_vector_type(8))) __bf16 bf16x8;
typedef __attribute__((ext_vector_type(4))) __bf16 bf16x4;
typedef __attribute__((ext_vector_type(4))) float f32x4;

// LDS map (bf16 elems), one 512-thread block, wave w = head w:
//   XN   [0,5120)                      xn [128][LDX]  (shared; dead after proj)
//   SCR(w) = 5120 + w*8192:
//     q_/prod [SCR, SCR+5120)          q[s][f] then prod[q][e]  [128][LDX]
//     kv      [SCR+5120, SCR+7680)     K[32][LDX] @0 | vT[32][LDX] @1280 | P-half [64][LDX] @0
//     (512-elem pad)
//   total 5120 + 8*8192 = 70656 elems = 141312 B -> 1 block/CU, 8 waves/CU.
// After B2 all of the above is dead; f32 partials part[w][128][32] overlay R
// (8*4096 f32 = 131072 B <= 141312).

// 1/sqrt(32)*log2(e), folded into wq (cvt_w) and bq seed; softmax uses m=0
// (shift-invariant; |scores| O(5) for LN'd data -> exp2 safe).
#define CQ 0.25505644061151687f

__global__ void cvt_w(const float* __restrict__ wq, const float* __restrict__ wk,
                      const float* __restrict__ wv, const float* __restrict__ wo,
                      __bf16* __restrict__ ws) {
  int i = blockIdx.x * blockDim.x + threadIdx.x;  // 0..32767
  const float* src = (i < 8192) ? wq : (i < 16384) ? wk : (i < 24576) ? wv : wo;
  float v = src[i & 8191];
  if (i < 8192) v *= CQ;
  ws[i] = (__bf16)v;
}

// 16-lane butterfly sum on the VALU pipe (DPP), no LDS traffic.
__device__ __forceinline__ float row_reduce_add16(float v) {
  int t;
  t = __builtin_amdgcn_update_dpp(0, __float_as_int(v), 0xB1, 0xF, 0xF, true);
  v += __int_as_float(t);
  t = __builtin_amdgcn_update_dpp(0, __float_as_int(v), 0x4E, 0xF, 0xF, true);
  v += __int_as_float(t);
  t = __builtin_amdgcn_update_dpp(0, __float_as_int(v), 0x141, 0xF, 0xF, true);
  v += __int_as_float(t);
  t = __builtin_amdgcn_update_dpp(0, __float_as_int(v), 0x140, 0xF, 0xF, true);
  v += __int_as_float(t);
  return v;
}

__global__ __launch_bounds__(TPB, 2) void mha_fused(
    const float* __restrict__ x, const float* __restrict__ gamma,
    const float* __restrict__ beta, const float* __restrict__ bq,
    const float* __restrict__ bk, const float* __restrict__ bv,
    const float* __restrict__ bo, const __bf16* __restrict__ wbf,
    float* __restrict__ out) {
  __shared__ __align__(16) __bf16 R[70656];
  __shared__ float red2[16];

  const int b = blockIdx.x;
  const int tid = threadIdx.x;
  const int lane = tid & 63;
  const int wid = tid >> 6;   // 0..7 == head index
  const int l15 = lane & 15;
  const int lh = lane >> 4;   // 0..3

  const __bf16* wqb = wbf;
  const __bf16* wkb = wbf + 8192;
  const __bf16* wvb = wbf + 16384;
  const __bf16* wob = wbf + 24576;  // [32][256] row-major

  const float* xb = x + b * INSZ;
  const f32x4 fz = {0.f, 0.f, 0.f, 0.f};

  // ---------------- LayerNorm (8 elems/thread) ----------------
  float xv[8];
  {
    float4 a0 = ((const float4*)(xb + tid * 8))[0];
    float4 a1 = ((const float4*)(xb + tid * 8))[1];
    xv[0] = a0.x; xv[1] = a0.y; xv[2] = a0.z; xv[3] = a0.w;
    xv[4] = a1.x; xv[5] = a1.y; xv[6] = a1.z; xv[7] = a1.w;
  }
  float s = 0.f, sq = 0.f;
#pragma unroll
  for (int i = 0; i < 8; ++i) { s += xv[i]; sq += xv[i] * xv[i]; }
#pragma unroll
  for (int o = 32; o > 0; o >>= 1) { s += __shfl_down(s, o); sq += __shfl_down(sq, o); }
  if (lane == 0) { red2[wid] = s; red2[8 + wid] = sq; }
  __syncthreads();
  s = 0.f; sq = 0.f;
#pragma unroll
  for (int i = 0; i < 8; ++i) { s += red2[i]; sq += red2[8 + i]; }
  const float mu = s * (1.f / INSZ);
  const float var = fmaxf(sq * (1.f / INSZ) - mu * mu, 0.f);
  const float rs = rsqrtf(var + 1e-5f);
  {
    int base = tid * 8;
    int row = base >> 5, col = base & 31;
    float4 g0 = ((const float4*)(gamma + base))[0];
    float4 g1 = ((const float4*)(gamma + base))[1];
    float4 b0 = ((const float4*)(beta + base))[0];
    float4 b1 = ((const float4*)(beta + base))[1];
    float gg[8] = {g0.x, g0.y, g0.z, g0.w, g1.x, g1.y, g1.z, g1.w};
    float bb[8] = {b0.x, b0.y, b0.z, b0.w, b1.x, b1.y, b1.z, b1.w};
    bf16x8 xe;
#pragma unroll
    for (int i = 0; i < 8; ++i) xe[i] = (__bf16)((xv[i] - mu) * rs * gg[i] + bb[i]);
    *(bf16x8*)&R[row * LDX + col] = xe;
  }
  __syncthreads();  // B1: xn ready for all waves

  const int h = wid;
  const int f0 = h * 32;
  __bf16* q_ = &R[5120 + wid * 8192];
  __bf16* kv = q_ + 5120;
  const __bf16* xn = &R[0];

  // ---------- q-proj (transposed): D[f][s] = wq · xn^T, 16 MFMAs ----------
  {
    bf16x8 wqf0 = *(const bf16x8*)&wqb[(f0 + l15) * 32 + lh * 8];
    bf16x8 wqf1 = *(const bf16x8*)&wqb[(f0 + 16 + l15) * 32 + lh * 8];
    f32x4 bq40 = *(const f32x4*)&bq[f0 + lh * 4];
    f32x4 bq41 = *(const f32x4*)&bq[f0 + 16 + lh * 4];
#pragma unroll
    for (int r = 0; r < 4; ++r) { bq40[r] *= CQ; bq41[r] *= CQ; }
#pragma unroll
    for (int st = 0; st < 8; ++st) {
      bf16x8 tB = *(const bf16x8*)&xn[(st * 16 + l15) * LDX + lh * 8];
      f32x4 d0 = __builtin_amdgcn_mfma_f32_16x16x32_bf16(wqf0, tB, bq40, 0, 0, 0);
      f32x4 d1 = __builtin_amdgcn_mfma_f32_16x16x32_bf16(wqf1, tB, bq41, 0, 0, 0);
      bf16x4 p0, p1;
#pragma unroll
      for (int r = 0; r < 4; ++r) { p0[r] = (__bf16)d0[r]; p1[r] = (__bf16)d1[r]; }
      *(bf16x4*)&q_[(st * 16 + l15) * LDX + lh * 4] = p0;        // q[s][f], f-tile 0
      *(bf16x4*)&q_[(st * 16 + l15) * LDX + 16 + lh * 4] = p1;   // f-tile 1
    }
  }

  // PV accumulator D[e][q]: 2 e-tiles x 8 q-tiles
  f32x4 p2[2][8];
#pragma unroll
  for (int i = 0; i < 2; ++i)
#pragma unroll
    for (int j = 0; j < 8; ++j) p2[i][j] = fz;

  // ---------------- key strips: 4 x 32 keys ----------------
  for (int sj = 0; sj < 4; ++sj) {
    const int jb = sj * 32;
    bf16x8 x0 = *(const bf16x8*)&xn[(jb + l15) * LDX + lh * 8];
    bf16x8 x1 = *(const bf16x8*)&xn[(jb + 16 + l15) * LDX + lh * 8];

    // k-proj (transposed) -> K[sLocal][f] in kv[0,1280)
    {
      bf16x8 wkf0 = *(const bf16x8*)&wkb[(f0 + l15) * 32 + lh * 8];
      bf16x8 wkf1 = *(const bf16x8*)&wkb[(f0 + 16 + l15) * 32 + lh * 8];
      f32x4 bk40 = *(const f32x4*)&bk[f0 + lh * 4];
      f32x4 bk41 = *(const f32x4*)&bk[f0 + 16 + lh * 4];
      f32x4 d00 = __builtin_amdgcn_mfma_f32_16x16x32_bf16(wkf0, x0, bk40, 0, 0, 0);
      f32x4 d01 = __builtin_amdgcn_mfma_f32_16x16x32_bf16(wkf0, x1, bk40, 0, 0, 0);
      f32x4 d10 = __builtin_amdgcn_mfma_f32_16x16x32_bf16(wkf1, x0, bk41, 0, 0, 0);
      f32x4 d11 = __builtin_amdgcn_mfma_f32_16x16x32_bf16(wkf1, x1, bk41, 0, 0, 0);
      bf16x4 q00, q01, q10, q11;
#pragma unroll
      for (int r = 0; r < 4; ++r) {
        q00[r] = (__bf16)d00[r]; q01[r] = (__bf16)d01[r];
        q10[r] = (__bf16)d10[r]; q11[r] = (__bf16)d11[r];
      }
      *(bf16x4*)&kv[(l15) * LDX + lh * 4] = q00;
      *(bf16x4*)&kv[(16 + l15) * LDX + lh * 4] = q01;
      *(bf16x4*)&kv[(l15) * LDX + 16 + lh * 4] = q10;
      *(bf16x4*)&kv[(16 + l15) * LDX + 16 + lh * 4] = q11;
    }
    bf16x8 ka0 = *(const bf16x8*)&kv[(l15) * LDX + lh * 8];
    bf16x8 ka1 = *(const bf16x8*)&kv[(16 + l15) * LDX + lh * 8];

    // v-proj (standard) -> vT[f][sLocal] in kv[1280,2560)
    {
      bf16x8 wvf0 = *(const bf16x8*)&wvb[(f0 + l15) * 32 + lh * 8];
      bf16x8 wvf1 = *(const bf16x8*)&wvb[(f0 + 16 + l15) * 32 + lh * 8];
      float bvs0 = bv[f0 + l15], bvs1 = bv[f0 + 16 + l15];
      f32x4 bv40 = {bvs0, bvs0, bvs0, bvs0};
      f32x4 bv41 = {bvs1, bvs1, bvs1, bvs1};
      f32x4 d00 = __builtin_amdgcn_mfma_f32_16x16x32_bf16(x0, wvf0, bv40, 0, 0, 0);
      f32x4 d01 = __builtin_amdgcn_mfma_f32_16x16x32_bf16(x1, wvf0, bv40, 0, 0, 0);
      f32x4 d10 = __builtin_amdgcn_mfma_f32_16x16x32_bf16(x0, wvf1, bv41, 0, 0, 0);
      f32x4 d11 = __builtin_amdgcn_mfma_f32_16x16x32_bf16(x1, wvf1, bv41, 0, 0, 0);
      bf16x4 q00, q01, q10, q11;
#pragma unroll
      for (int r = 0; r < 4; ++r) {
        q00[r] = (__bf16)d00[r]; q01[r] = (__bf16)d01[r];
        q10[r] = (__bf16)d10[r]; q11[r] = (__bf16)d11[r];
      }
      *(bf16x4*)&kv[1280 + (l15) * LDX + lh * 4] = q00;        // vT rows e=l15, j-run jt0
      *(bf16x4*)&kv[1280 + (l15) * LDX + 16 + lh * 4] = q01;   // jt1
      *(bf16x4*)&kv[1280 + (16 + l15) * LDX + lh * 4] = q10;
      *(bf16x4*)&kv[1280 + (16 + l15) * LDX + 16 + lh * 4] = q11;
    }
    bf16x8 va0 = *(const bf16x8*)&kv[1280 + (l15) * LDX + lh * 8];
    bf16x8 va1 = *(const bf16x8*)&kv[1280 + (16 + l15) * LDX + lh * 8];

    // scores^T strip: D[j][i], j = jb + mt*16+lh*4+r, i = it*16+l15
    f32x4 st_[2][8];
    __builtin_amdgcn_s_setprio(1);
#pragma unroll
    for (int it = 0; it < 8; ++it) {
      bf16x8 qb = *(const bf16x8*)&q_[(it * 16 + l15) * LDX + lh * 8];
      st_[0][it] = __builtin_amdgcn_mfma_f32_16x16x32_bf16(ka0, qb, fz, 0, 0, 0);
      st_[1][it] = __builtin_amdgcn_mfma_f32_16x16x32_bf16(ka1, qb, fz, 0, 0, 0);
    }
    __builtin_amdgcn_s_setprio(0);

    // softmax over query axis (m=0): per j, sum over (it, l15) via DPP
    float inv[2][4];
#pragma unroll
    for (int mt = 0; mt < 2; ++mt)
#pragma unroll
      for (int r = 0; r < 4; ++r) {
        float ssum = 0.f;
#pragma unroll
        for (int it = 0; it < 8; ++it) {
          float e = __builtin_amdgcn_exp2f(st_[mt][it][r]);
          st_[mt][it][r] = e;
          ssum += e;
        }
        ssum = row_reduce_add16(ssum);
        inv[mt][r] = __builtin_amdgcn_rcpf(ssum);
      }

    // P in i-halves (64 rows each) through kv[0,2560), then PV accumulate
#pragma unroll
    for (int half = 0; half < 2; ++half) {
#pragma unroll
      for (int mt = 0; mt < 2; ++mt)
#pragma unroll
        for (int it4 = 0; it4 < 4; ++it4) {
          int it = half * 4 + it4;
          bf16x4 pp;
#pragma unroll
          for (int r = 0; r < 4; ++r) pp[r] = (__bf16)(st_[mt][it][r] * inv[mt][r]);
          *(bf16x4*)&kv[(it4 * 16 + l15) * LDX + mt * 16 + lh * 4] = pp;
        }
      __builtin_amdgcn_s_setprio(1);
#pragma unroll
      for (int qt = 0; qt < 4; ++qt) {
        bf16x8 pb = *(const bf16x8*)&kv[(qt * 16 + l15) * LDX + lh * 8];
        int g = half * 4 + qt;
        p2[0][g] = __builtin_amdgcn_mfma_f32_16x16x32_bf16(va0, pb, p2[0][g], 0, 0, 0);
        p2[1][g] = __builtin_amdgcn_mfma_f32_16x16x32_bf16(va1, pb, p2[1][g], 0, 0, 0);
      }
      __builtin_amdgcn_s_setprio(0);
    }
  }

  // ---------- prod stash (overwrites q_): prod[q][e] ----------
#pragma unroll
  for (int et = 0; et < 2; ++et)
#pragma unroll
    for (int g = 0; g < 8; ++g) {
      bf16x4 pp;
#pragma unroll
      for (int r = 0; r < 4; ++r) pp[r] = (__bf16)p2[et][g][r];
      *(bf16x4*)&q_[(g * 16 + l15) * LDX + et * 16 + lh * 4] = pp;
    }

  // ---------- outproj (transposed): D[e'][q] = wo_h · prod^T ----------
  f32x4 oc[2][8];
  {
    bf16x8 wo0 = *(const bf16x8*)&wob[(l15) * 256 + h * 32 + lh * 8];
    bf16x8 wo1 = *(const bf16x8*)&wob[(16 + l15) * 256 + h * 32 + lh * 8];
#pragma unroll
    for (int g = 0; g < 8; ++g) {
      bf16x8 aa = *(const bf16x8*)&q_[(g * 16 + l15) * LDX + lh * 8];
      oc[0][g] = __builtin_amdgcn_mfma_f32_16x16x32_bf16(wo0, aa, fz, 0, 0, 0);
      oc[1][g] = __builtin_amdgcn_mfma_f32_16x16x32_bf16(wo1, aa, fz, 0, 0, 0);
    }
  }
  __syncthreads();  // B2: all xn/scratch reads done -> overlay f32 partials

  // part[w][q][e'] f32, overlaid on R
  {
    float* pw = (float*)R + wid * 4096;
#pragma unroll
    for (int nt = 0; nt < 2; ++nt)
#pragma unroll
      for (int g = 0; g < 8; ++g)
        *(f32x4*)&pw[(g * 16 + l15) * 32 + nt * 16 + lh * 4] = oc[nt][g];
  }
  __syncthreads();  // B3: partials ready

  // ---------- final: out = sum_w part + bo + x ----------
  {
    int base = tid * 8;
    int col = base & 31;
    const float* pr = (const float*)R;
    f32x4 s0 = fz, s1 = fz;
#pragma unroll
    for (int w = 0; w < 8; ++w) {
      s0 += *(const f32x4*)&pr[w * 4096 + base];
      s1 += *(const f32x4*)&pr[w * 4096 + base + 4];
    }
    f32x4 bo0 = *(const f32x4*)&bo[col];
    f32x4 bo1 = *(const f32x4*)&bo[col + 4];
    f32x4 xr0 = *(const f32x4*)&xb[base];
    f32x4 xr1 = *(const f32x4*)&xb[base + 4];
    *(f32x4*)&out[b * INSZ + base] = s0 + bo0 + xr0;
    *(f32x4*)&out[b * INSZ + base + 4] = s1 + bo1 + xr1;
  }
}

extern "C" void kernel_launch(void* const* d_in, const int* in_sizes, int n_in,
                              void* d_out, int out_size, void* d_ws, size_t ws_size,
                              hipStream_t stream) {
  const float* x = (const float*)d_in[0];
  const float* gamma = (const float*)d_in[1];
  const float* beta = (const float*)d_in[2];
  const float* wq = (const float*)d_in[3];
  const float* bq = (const float*)d_in[4];
  const float* wk = (const float*)d_in[5];
  const float* bk = (const float*)d_in[6];
  const float* wv = (const float*)d_in[7];
  const float* bv = (const float*)d_in[8];
  const float* wo = (const float*)d_in[9];
  const float* bo = (const float*)d_in[10];
  float* out = (float*)d_out;
  __bf16* wsb = (__bf16*)d_ws;

  cvt_w<<<128, 256, 0, stream>>>(wq, wk, wv, wo, wsb);
  mha_fused<<<BATCH, TPB, 0, stream>>>(x, gamma, beta, bq, bk, bv, bo, wsb, out);
}